// Round 10
// baseline (376.134 us; speedup 1.0000x reference)
//
#include <hip/hip_runtime.h>

// OT_GNN: 2x GCN -> per-node fused-GW distance to 10 templates -> linear head.
// R10: gemm1 = LDS-staged MFMA. Diagnosis across R5-R9: scalar gemm1 (110us)
// stalls 83% on wave-uniform broadcast x-loads; MFMA variants stalled on
// scattered A-frag loads (R7/R8) or serialized W staging (R6). Fix: block
// stages 16 x-rows (16.6KB, +8 pad -> uniform 8 words/bank) via coalesced
// loads; 4 waves run the PROVEN R8 MFMA path with A from LDS ds_read_b128
// and B from the proven Wp pre-swizzle (L2-hot). gemm2-in-gatherA fusion,
// inline dinv, and LDS epilogue (R9) retained.
// Certificate (R4): K = exp(-5(M+tens)) == 0 exactly in fp32 when
// (sqrt(tn2min)-sqrt(xn2max))^2 >= 26, since tens >= -2 => dist == 0 exact.

#define NN   20000
#define EE   320000
#define FIN  512
#define HID  64
#define KNEI 8
#define LSZ  9      // K_NEI + 1
#define NTPL 10
#define NTN  8
#define NCLS 6
#define CAP  48     // bucket capacity per node (max in-degree ~34)
#define XPAD 8      // bf16 elements of row padding in gemm1 LDS tile

typedef unsigned short bf16_t;
typedef unsigned short us8 __attribute__((ext_vector_type(8)));
typedef short s16x8 __attribute__((ext_vector_type(8)));
typedef float f32x4 __attribute__((ext_vector_type(4)));

__device__ __forceinline__ float b2f(bf16_t u) {
  union { unsigned int i; float f; } v; v.i = ((unsigned int)u) << 16; return v.f;
}
__device__ __forceinline__ bf16_t f2b(float f) {
  union { float f; unsigned int i; } v; v.f = f;
  unsigned int x = v.i;
  return (bf16_t)((x + 0x7fffu + ((x >> 16) & 1u)) >> 16);  // RNE
}
__device__ __forceinline__ float ldf(const void* p, long i, int fp32) {
  return fp32 ? ((const float*)p)[i] : b2f(((const bf16_t*)p)[i]);
}
__device__ __forceinline__ int ldi(const void* p, long i, int i64) {
  return i64 ? (int)((const long long*)p)[i] : ((const int*)p)[i];
}
__device__ __forceinline__ float frcp(float x) { return __builtin_amdgcn_rcpf(x); }

// ---------- dtype probe + template row-norm mins ----------
__global__ __launch_bounds__(128) void probe_kernel(const void* __restrict__ x,
                                                    const void* __restrict__ ei,
                                                    const void* __restrict__ tfeat,
                                                    int* __restrict__ flags,
                                                    float* __restrict__ tn2min) {
  __shared__ int sfl[2];
  __shared__ float tn2s[80];
  int tid = threadIdx.x;
  if (tid == 0) {
    int sane = 0;
    for (int k = 0; k < 64; k += 2) {
      bf16_t u = ((const bf16_t*)x)[k];
      int e = (u >> 7) & 0xff;
      if (e >= 112 && e <= 142) sane++;
    }
    int f0 = (sane < 24) ? 1 : 0;
    int zc = 0;
    for (int k = 1; k < 64; k += 2)
      if (((const int*)ei)[k] == 0) zc++;
    int f1 = (zc >= 16) ? 1 : 0;
    flags[0] = f0; flags[1] = f1;
    sfl[0] = f0; sfl[1] = f1;
  }
  __syncthreads();
  if (tid < 80) {
    int fF = sfl[0];
    float s = 0.f;
    for (int k = 0; k < HID; ++k) {
      float v = ldf(tfeat, (long)tid * HID + k, fF);
      s += v * v;
    }
    tn2s[tid] = s;
  }
  __syncthreads();
  if (tid == 0) {
    float gmin = 1e30f;
    for (int t = 0; t < NTPL; ++t) {
      float m = tn2s[t * 8];
      for (int r = 1; r < 8; ++r) m = fminf(m, tn2s[t * 8 + r]);
      tn2min[t] = m;
      gmin = fminf(gmin, m);
    }
    tn2min[NTPL] = gmin;
  }
}

// ---------- W1 pre-swizzle into B-fragment lane order (proven R7/R8) -------
// Wp[(kk*4+nt)*64 + lane] (s16x8), element j = W1[k*HID+n],
// k = kk*32 + (lane>>4)*8 + j, n = nt*16 + (lane&15).
__global__ __launch_bounds__(256) void wswz_kernel(const void* __restrict__ W1,
                                                   bf16_t* __restrict__ Wp,
                                                   const int* __restrict__ flags) {
  if (flags[0]) return;
  int idx = blockIdx.x * 256 + threadIdx.x;   // 0..32767
  int j = idx & 7;
  int lane = (idx >> 3) & 63;
  int nt = (idx >> 9) & 3;
  int kk = idx >> 11;
  int k = kk * 32 + (lane >> 4) * 8 + j;
  int n = nt * 16 + (lane & 15);
  Wp[idx] = ((const bf16_t*)W1)[k * HID + n];
}

// ---------- bucket scatter: pos becomes in-degree, slot holds sources -------
__global__ __launch_bounds__(256) void scatter_kernel(const void* __restrict__ ei,
                                                      int* __restrict__ pos,
                                                      int* __restrict__ slot,
                                                      const int* __restrict__ flags) {
  int i = blockIdx.x * 256 + threadIdx.x;
  if (i >= EE) return;
  int i64 = flags[1];
  int s = ldi(ei, i, i64);
  int d = ldi(ei, (long)EE + i, i64);
  int p = atomicAdd(&pos[d], 1);
  if (p < CAP) slot[d * CAP + p] = s;
}

// ---------- GEMM1: LDS-staged x + MFMA (R8 math, coalesced staging) --------
__global__ __launch_bounds__(256) void gemm1_kernel(const void* __restrict__ x,
                                                    const bf16_t* __restrict__ Wp,
                                                    const void* __restrict__ W1,
                                                    float* __restrict__ xw1,
                                                    const int* __restrict__ flags) {
  __shared__ bf16_t xs[16][FIN + XPAD];   // 16 rows, +8 pad (16.6 KB)
  const int tid = threadIdx.x;
  const int wv = tid >> 6;                // wave = n-tile
  const int lane = tid & 63;
  const int row0 = blockIdx.x * 16;
  if (!flags[0]) {
    // stage 16 rows coalesced: thread t loads 64 B of row t>>4
    {
      const int r = tid >> 4, cb = (tid & 15) * 32;   // 32 bf16 = 64 B
      const bf16_t* src = (const bf16_t*)x + (long)(row0 + r) * FIN + cb;
#pragma unroll
      for (int i = 0; i < 4; ++i)
        *(us8*)&xs[r][cb + i * 8] = *(const us8*)(src + i * 8);
    }
    __syncthreads();
    // A-frag from LDS: A[m][k], m=lane&15, k=(lane>>4)*8 + j (+32 per kk)
    const int m = lane & 15, q = lane >> 4;
    const s16x8* wp = (const s16x8*)Wp + wv * 64 + lane;
    f32x4 acc = {0.f, 0.f, 0.f, 0.f};
#pragma unroll
    for (int kk = 0; kk < 16; ++kk) {
      s16x8 a = *(const s16x8*)&xs[m][q * 8 + kk * 32];
      s16x8 b = wp[kk * 256];
      acc = __builtin_amdgcn_mfma_f32_16x16x32_bf16(a, b, acc, 0, 0, 0);
    }
    // C/D: col = lane&15 (+wv*16), row = (lane>>4)*4 + reg   [proven]
    const int rbase = row0 + q * 4;
    const int c = wv * 16 + m;
#pragma unroll
    for (int r = 0; r < 4; ++r)
      xw1[(long)(rbase + r) * HID + c] = acc[r];
  } else {
    // fp32 fallback: 4 rows per wave
    const float* wp = (const float*)W1;
    for (int r = wv * 4; r < wv * 4 + 4; ++r) {
      const float* x0 = (const float*)x + (long)(row0 + r) * FIN;
      float a = 0.f;
      for (int k = 0; k < FIN; ++k) a += x0[k] * wp[k * HID + lane];
      xw1[(long)(row0 + r) * HID + lane] = a;
    }
  }
}

// ---------- gather A: h1 = relu(Agg(xw1)+b1); xw2 = h1 @ W2 (in-wave GEMV) --
__global__ __launch_bounds__(256) void gatherA_kernel(const float* __restrict__ xw,
                                                      const int* __restrict__ cnt,
                                                      const int* __restrict__ slot,
                                                      float* __restrict__ xw2,
                                                      const void* __restrict__ b1v,
                                                      const void* __restrict__ W2,
                                                      const int* __restrict__ flags) {
  int n = blockIdx.x * 4 + (threadIdx.x >> 6);
  if (n >= NN) return;
  int fF = flags[0];
  int c = threadIdx.x & 63;
  float dn = rsqrtf((float)cnt[n] + 1.0f);
  float acc = xw[(long)n * HID + c] * dn;      // self term
  int m = cnt[n]; if (m > CAP) m = CAP;
  const int* sl = slot + (long)n * CAP;
  float accB = 0.f;
  for (int e0 = 0; e0 < m; e0 += 8) {
    int4 sa = *(const int4*)(sl + e0);
    int4 sb = *(const int4*)(sl + e0 + 4);
    if (e0 + 0 < m) acc  += xw[(long)sa.x * HID + c] * rsqrtf((float)cnt[sa.x] + 1.0f);
    if (e0 + 1 < m) accB += xw[(long)sa.y * HID + c] * rsqrtf((float)cnt[sa.y] + 1.0f);
    if (e0 + 2 < m) acc  += xw[(long)sa.z * HID + c] * rsqrtf((float)cnt[sa.z] + 1.0f);
    if (e0 + 3 < m) accB += xw[(long)sa.w * HID + c] * rsqrtf((float)cnt[sa.w] + 1.0f);
    if (e0 + 4 < m) acc  += xw[(long)sb.x * HID + c] * rsqrtf((float)cnt[sb.x] + 1.0f);
    if (e0 + 5 < m) accB += xw[(long)sb.y * HID + c] * rsqrtf((float)cnt[sb.y] + 1.0f);
    if (e0 + 6 < m) acc  += xw[(long)sb.z * HID + c] * rsqrtf((float)cnt[sb.z] + 1.0f);
    if (e0 + 7 < m) accB += xw[(long)sb.w * HID + c] * rsqrtf((float)cnt[sb.w] + 1.0f);
  }
  float h1 = (acc + accB) * dn + ldf(b1v, c, fF);
  h1 = h1 > 0.f ? h1 : 0.f;                     // relu'd hidden, channel c

  // xw2[n][c] = sum_k h1[k] * W2[k][c]  via 64 wave broadcasts
  float o = 0.f;
#pragma unroll 8
  for (int k = 0; k < HID; ++k)
    o += __shfl(h1, k) * ldf(W2, k * HID + c, fF);
  xw2[(long)n * HID + c] = o;
}

// ---------- gather B: h2 = Agg(xw2); n2 = ||h2+b2||^2 ----------
__global__ __launch_bounds__(256) void gatherB_kernel(const float* __restrict__ xw,
                                                      const int* __restrict__ cnt,
                                                      const int* __restrict__ slot,
                                                      float* __restrict__ h,
                                                      float* __restrict__ n2,
                                                      const void* __restrict__ b2v,
                                                      const int* __restrict__ flags) {
  int n = blockIdx.x * 4 + (threadIdx.x >> 6);
  if (n >= NN) return;
  int c = threadIdx.x & 63;
  float dn = rsqrtf((float)cnt[n] + 1.0f);
  float acc = xw[(long)n * HID + c] * dn;
  int m = cnt[n]; if (m > CAP) m = CAP;
  const int* sl = slot + (long)n * CAP;
  float accB = 0.f;
  for (int e0 = 0; e0 < m; e0 += 8) {
    int4 sa = *(const int4*)(sl + e0);
    int4 sb = *(const int4*)(sl + e0 + 4);
    if (e0 + 0 < m) acc  += xw[(long)sa.x * HID + c] * rsqrtf((float)cnt[sa.x] + 1.0f);
    if (e0 + 1 < m) accB += xw[(long)sa.y * HID + c] * rsqrtf((float)cnt[sa.y] + 1.0f);
    if (e0 + 2 < m) acc  += xw[(long)sa.z * HID + c] * rsqrtf((float)cnt[sa.z] + 1.0f);
    if (e0 + 3 < m) accB += xw[(long)sa.w * HID + c] * rsqrtf((float)cnt[sa.w] + 1.0f);
    if (e0 + 4 < m) acc  += xw[(long)sb.x * HID + c] * rsqrtf((float)cnt[sb.x] + 1.0f);
    if (e0 + 5 < m) accB += xw[(long)sb.y * HID + c] * rsqrtf((float)cnt[sb.y] + 1.0f);
    if (e0 + 6 < m) acc  += xw[(long)sb.z * HID + c] * rsqrtf((float)cnt[sb.z] + 1.0f);
    if (e0 + 7 < m) accB += xw[(long)sb.w * HID + c] * rsqrtf((float)cnt[sb.w] + 1.0f);
  }
  acc = (acc + accB) * dn;
  h[(long)n * HID + c] = acc;
  float v = acc + ldf(b2v, c, flags[0]);
  float s = v * v;
  s += __shfl_xor(s, 1); s += __shfl_xor(s, 2); s += __shfl_xor(s, 4);
  s += __shfl_xor(s, 8); s += __shfl_xor(s, 16); s += __shfl_xor(s, 32);
  if (c == 0) n2[n] = s;
}

// ---------- FGW: 4 nodes/block, 8-lane octet per (node, template) ----------
#define NODES_PB 4
#define TPN 80            // threads per node (10 templates x 8 lanes)
#define XLP 65            // padded xl row stride

__global__ __launch_bounds__(320, 2) void fgw_kernel(
    const float* __restrict__ h2,        // [NN,64] fp32 ws (pre-b2)
    const void* __restrict__ b2v,
    const void* __restrict__ nbr_idx,
    const void* __restrict__ nbr_mask,
    const void* __restrict__ C_local,
    const void* __restrict__ tmpl,       // [10,8,8]
    const void* __restrict__ tfeat,      // [10,8,64]
    const void* __restrict__ Wlin,       // [74,6]
    const void* __restrict__ blin,       // [6]
    void* __restrict__ out,              // [NN,6]
    const int* __restrict__ flags,
    const float* __restrict__ tn2min,    // [11]: per-t mins + global min
    const float* __restrict__ n2)        // [NN] node norm^2
{
  const int tid = threadIdx.x;
  const int fF = flags[0];
  const int fI = flags[1];
  const int nb = tid / TPN;
  const int local = tid - nb * TPN;      // [0,80)
  const int t = local >> 3;
  const int j = local & 7;
  const int n = blockIdx.x * NODES_PB + nb;
  const int lane = tid & 63;
  const int ob = lane & 56;

  __shared__ float xlS[NODES_PB][LSZ][XLP];
  __shared__ float C1S[NODES_PB][81];
  __shared__ float hwS[NODES_PB][LSZ];
  __shared__ float f1S[NODES_PB][LSZ];
  __shared__ float xnS[NODES_PB][LSZ];
  __shared__ float distS[NODES_PB][NTPL];
  __shared__ float xmaxS[NODES_PB];
  __shared__ int   needS[NODES_PB];
  __shared__ int   sidxS[NODES_PB][LSZ];
  __shared__ float WlinS[(HID + NTPL) * NCLS + NCLS];   // Wlin + blin

  for (int i = tid; i < (HID + NTPL) * NCLS; i += 320)
    WlinS[i] = ldf(Wlin, i, fF);
  if (tid < NCLS) WlinS[(HID + NTPL) * NCLS + tid] = ldf(blin, tid, fF);

  if (local < LSZ) {
    int idx = (local == 0) ? n : ldi(nbr_idx, (long)n * KNEI + local - 1, fI);
    sidxS[nb][local] = idx;
    xnS[nb][local] = n2[idx];
  }
  if (local < HID)
    xlS[nb][0][local] = h2[(long)n * HID + local] + ldf(b2v, local, fF);
  __syncthreads();   // B1

  if (local == 0) {
    float xm = xnS[nb][0];
#pragma unroll
    for (int l = 1; l < LSZ; ++l) xm = fmaxf(xm, xnS[nb][l]);
    xmaxS[nb] = xm;
    needS[nb] = ((sqrtf(tn2min[NTPL]) - sqrtf(xm)) >= 5.0990195f) ? 0 : 1;
  }
  __syncthreads();   // B2

  const int need = needS[nb];
  if (need) {
    for (int i = local; i < 8 * HID; i += TPN) {
      int l = 1 + (i >> 6), k = i & 63;
      xlS[nb][l][k] = h2[(long)sidxS[nb][l] * HID + k] + ldf(b2v, k, fF);
    }
    for (int i = local; i < 81; i += TPN)
      C1S[nb][i] = ldf(C_local, (long)n * 81 + i, fF);
  }
  __syncthreads();   // B3

  if (need && local < LSZ) {
    int l = local;
    float msum = 0.f, f1 = 0.f;
#pragma unroll
    for (int jj = 0; jj < LSZ; ++jj) {
      float mj = ldf(nbr_mask, (long)n * LSZ + jj, fF);
      msum += mj;
      float c = C1S[nb][l * LSZ + jj];
      f1 += c * c * mj;
    }
    float inv = frcp(msum);
    hwS[nb][l] = ldf(nbr_mask, (long)n * LSZ + l, fF) * inv;
    f1S[nb][l] = f1 * inv;
  }
  __syncthreads();   // B4

  bool slow = need && ((sqrtf(tn2min[t]) - sqrtf(xmaxS[nb])) < 5.0990195f);
  if (slow) {
    float C2c[NTN];
    float f2h2;
    {
      float s = 0.f;
#pragma unroll
      for (int m = 0; m < NTN; ++m) {
        C2c[m] = ldf(tmpl, t * 64 + m * 8 + j, fF);
        float r = ldf(tmpl, t * 64 + j * 8 + m, fF);
        s += r * r;
      }
      f2h2 = s * 0.125f;
    }
    float hwr[LSZ], f1r[LSZ];
#pragma unroll
    for (int l = 0; l < LSZ; ++l) { hwr[l] = hwS[nb][l]; f1r[l] = f1S[nb][l]; }

    float Mc[LSZ];
    {
      float accI[LSZ];
#pragma unroll
      for (int l = 0; l < LSZ; ++l) accI[l] = 0.f;
      float tn2 = 0.f;
      const long tb = (long)local * HID;
      for (int kb = 0; kb < 8; ++kb) {
        float r[8];
#pragma unroll
        for (int q = 0; q < 8; ++q) r[q] = ldf(tfeat, tb + kb * 8 + q, fF);
#pragma unroll
        for (int q = 0; q < 8; ++q) tn2 += r[q] * r[q];
#pragma unroll
        for (int l = 0; l < LSZ; ++l) {
          float s = 0.f;
#pragma unroll
          for (int q = 0; q < 8; ++q) s += xlS[nb][l][kb * 8 + q] * r[q];
          accI[l] += s;
        }
      }
#pragma unroll
      for (int l = 0; l < LSZ; ++l)
        Mc[l] = xnS[nb][l] + tn2 - 2.f * accI[l];
    }

    float Tc[LSZ], Kc[LSZ], u[LSZ];
#pragma unroll
    for (int l = 0; l < LSZ; ++l) Tc[l] = hwr[l] * 0.125f;

    float v = 1.0f;
    for (int outer = 0; outer < 3; ++outer) {
      float Ac[LSZ];
#pragma unroll
      for (int l = 0; l < LSZ; ++l) {
        float s = 0.f;
#pragma unroll
        for (int l2 = 0; l2 < LSZ; ++l2) s += C1S[nb][l * LSZ + l2] * Tc[l2];
        Ac[l] = s;
      }
#pragma unroll
      for (int l = 0; l < LSZ; ++l) {
        float s = 0.f;
#pragma unroll
        for (int m = 0; m < NTN; ++m) s += __shfl(Ac[l], ob + m) * C2c[m];
        float tens = f1r[l] + f2h2 - 2.f * s;
        Kc[l] = __expf(-5.0f * (Mc[l] + tens));
      }
      v = 1.0f;
      for (int it = 0; it < 5; ++it) {
#pragma unroll
        for (int l = 0; l < LSZ; ++l) {
          float p = Kc[l] * v;
          p += __shfl_xor(p, 1); p += __shfl_xor(p, 2); p += __shfl_xor(p, 4);
          u[l] = hwr[l] * frcp(p + 1e-16f);
        }
        float s = 0.f;
#pragma unroll
        for (int l = 0; l < LSZ; ++l) s += Kc[l] * u[l];
        v = 0.125f * frcp(s + 1e-16f);
      }
#pragma unroll
      for (int l = 0; l < LSZ; ++l) Tc[l] = u[l] * Kc[l] * v;
    }
    {
      float Ac[LSZ];
#pragma unroll
      for (int l = 0; l < LSZ; ++l) {
        float s = 0.f;
#pragma unroll
        for (int l2 = 0; l2 < LSZ; ++l2) s += C1S[nb][l * LSZ + l2] * Tc[l2];
        Ac[l] = s;
      }
      float cl = 0.f;
#pragma unroll
      for (int l = 0; l < LSZ; ++l) {
        float s = 0.f;
#pragma unroll
        for (int m = 0; m < NTN; ++m) s += __shfl(Ac[l], ob + m) * C2c[m];
        float tens = f1r[l] + f2h2 - 2.f * s;
        cl += Tc[l] * 0.5f * (Mc[l] + tens);
      }
      cl += __shfl_xor(cl, 1); cl += __shfl_xor(cl, 2); cl += __shfl_xor(cl, 4);
      if (j == 0) distS[nb][t] = cl;
    }
  } else if (j == 0) {
    distS[nb][t] = 0.f;
  }
  __syncthreads();   // B5

  if (local < NCLS) {
    int c = local;
    float acc = WlinS[(HID + NTPL) * NCLS + c];
#pragma unroll
    for (int k = 0; k < HID; ++k)
      acc += xlS[nb][0][k] * WlinS[k * NCLS + c];
#pragma unroll
    for (int tt = 0; tt < NTPL; ++tt)
      acc += distS[nb][tt] * WlinS[(HID + tt) * NCLS + c];
    float r = acc > 0.f ? acc : 0.f;
    if (fF) ((float*)out)[(long)n * NCLS + c] = r;
    else    ((bf16_t*)out)[(long)n * NCLS + c] = f2b(r);
  }
}

extern "C" void kernel_launch(void* const* d_in, const int* in_sizes, int n_in,
                              void* d_out, int out_size, void* d_ws, size_t ws_size,
                              hipStream_t stream) {
  (void)in_sizes; (void)n_in; (void)out_size; (void)ws_size;
  const void* x     = d_in[0];
  const void* ei    = d_in[1];
  const void* nbr   = d_in[2];
  const void* nmask = d_in[3];
  const void* Cl    = d_in[4];
  const void* W1    = d_in[5];
  const void* b1    = d_in[6];
  const void* W2    = d_in[7];
  const void* b2    = d_in[8];
  const void* tmpl  = d_in[9];
  const void* tfeat = d_in[10];
  const void* Wlin  = d_in[11];
  const void* blin  = d_in[12];

  // ws layout (4B words): flags[4] | tn2min[12] | n2 NN | pos NN |
  //                       slot CAP*NN | Wp 16K words | bufA 64NN | bufB 64NN
  int*    flags  = (int*)d_ws;
  float*  tn2min = (float*)d_ws + 4;
  float*  n2     = (float*)d_ws + 16;
  int*    pos    = (int*)(n2 + NN);
  int*    slot   = pos + NN;
  bf16_t* Wp     = (bf16_t*)(slot + (long)CAP * NN);
  float*  bufA   = (float*)((int*)Wp + 16384);
  float*  bufB   = bufA + (long)NN * HID;

  probe_kernel<<<1, 128, 0, stream>>>(x, ei, tfeat, flags, tn2min);
  wswz_kernel<<<128, 256, 0, stream>>>(W1, Wp, flags);

  hipMemsetAsync(pos, 0, NN * sizeof(int), stream);
  scatter_kernel<<<(EE + 255) / 256, 256, 0, stream>>>(ei, pos, slot, flags);

  // layer 1 GEMM (LDS-staged MFMA)
  gemm1_kernel<<<NN / 16, 256, 0, stream>>>(x, Wp, W1, bufA, flags);
  // gather A: aggregate xw1 -> relu(h1) -> in-wave GEMV with W2 -> xw2 (bufB)
  gatherA_kernel<<<NN / 4, 256, 0, stream>>>(bufA, pos, slot, bufB, b1, W2, flags);
  // gather B: aggregate xw2 -> h2 (bufA) + n2
  gatherB_kernel<<<NN / 4, 256, 0, stream>>>(bufB, pos, slot, bufA, n2, b2, flags);

  fgw_kernel<<<NN / NODES_PB, 320, 0, stream>>>(bufA, b2, nbr, nmask, Cl, tmpl,
                                                tfeat, Wlin, blin, d_out, flags,
                                                tn2min, n2);
}

// Round 11
// 319.223 us; speedup vs baseline: 1.1783x; 1.1783x over previous
//
#include <hip/hip_runtime.h>

// OT_GNN: 2x GCN -> per-node fused-GW distance to 10 templates -> linear head.
// R11: gemm1 kept scalar (beats all 4 MFMA variants, R6-R10) but re-gridded
// to 2 rows/wave (10000 waves, 2x R9's overlap) AND fused with scatter into
// one dispatch via block-range split (independent work; scatter hides under
// gemm1's memory stalls). wswz dropped. gatherA(+gemm2 GEMV), gatherB(+n2),
// fgw with lazy staging + LDS epilogue retained from R9.
// Certificate (R4): K = exp(-5(M+tens)) == 0 exactly in fp32 when
// (sqrt(tn2min)-sqrt(xn2max))^2 >= 26, since tens >= -2 => dist == 0 exact.

#define NN   20000
#define EE   320000
#define FIN  512
#define HID  64
#define KNEI 8
#define LSZ  9      // K_NEI + 1
#define NTPL 10
#define NTN  8
#define NCLS 6
#define CAP  48     // bucket capacity per node (max in-degree ~34)
#define GB1  (NN / 8)          // gemm1 blocks (8 rows each)
#define SB1  (EE / 256)        // scatter blocks

typedef unsigned short bf16_t;
typedef unsigned short us8 __attribute__((ext_vector_type(8)));

__device__ __forceinline__ float b2f(bf16_t u) {
  union { unsigned int i; float f; } v; v.i = ((unsigned int)u) << 16; return v.f;
}
__device__ __forceinline__ bf16_t f2b(float f) {
  union { float f; unsigned int i; } v; v.f = f;
  unsigned int x = v.i;
  return (bf16_t)((x + 0x7fffu + ((x >> 16) & 1u)) >> 16);  // RNE
}
__device__ __forceinline__ float ldf(const void* p, long i, int fp32) {
  return fp32 ? ((const float*)p)[i] : b2f(((const bf16_t*)p)[i]);
}
__device__ __forceinline__ int ldi(const void* p, long i, int i64) {
  return i64 ? (int)((const long long*)p)[i] : ((const int*)p)[i];
}
__device__ __forceinline__ float frcp(float x) { return __builtin_amdgcn_rcpf(x); }

// ---------- dtype probe + template row-norm mins ----------
__global__ __launch_bounds__(128) void probe_kernel(const void* __restrict__ x,
                                                    const void* __restrict__ ei,
                                                    const void* __restrict__ tfeat,
                                                    int* __restrict__ flags,
                                                    float* __restrict__ tn2min) {
  __shared__ int sfl[2];
  __shared__ float tn2s[80];
  int tid = threadIdx.x;
  if (tid == 0) {
    int sane = 0;
    for (int k = 0; k < 64; k += 2) {
      bf16_t u = ((const bf16_t*)x)[k];
      int e = (u >> 7) & 0xff;
      if (e >= 112 && e <= 142) sane++;
    }
    int f0 = (sane < 24) ? 1 : 0;
    int zc = 0;
    for (int k = 1; k < 64; k += 2)
      if (((const int*)ei)[k] == 0) zc++;
    int f1 = (zc >= 16) ? 1 : 0;
    flags[0] = f0; flags[1] = f1;
    sfl[0] = f0; sfl[1] = f1;
  }
  __syncthreads();
  if (tid < 80) {
    int fF = sfl[0];
    float s = 0.f;
    for (int k = 0; k < HID; ++k) {
      float v = ldf(tfeat, (long)tid * HID + k, fF);
      s += v * v;
    }
    tn2s[tid] = s;
  }
  __syncthreads();
  if (tid == 0) {
    float gmin = 1e30f;
    for (int t = 0; t < NTPL; ++t) {
      float m = tn2s[t * 8];
      for (int r = 1; r < 8; ++r) m = fminf(m, tn2s[t * 8 + r]);
      tn2min[t] = m;
      gmin = fminf(gmin, m);
    }
    tn2min[NTPL] = gmin;
  }
}

// ---------- fused: gemm1 (blocks 0..GB1-1) | edge scatter (GB1..GB1+SB1-1) --
__global__ __launch_bounds__(256) void work1_kernel(const void* __restrict__ x,
                                                    const void* __restrict__ W1,
                                                    float* __restrict__ xw1,
                                                    const void* __restrict__ ei,
                                                    int* __restrict__ pos,
                                                    int* __restrict__ slot,
                                                    const int* __restrict__ flags) {
  const int b = blockIdx.x;
  if (b < GB1) {
    // gemm1: 8 rows/block, 2 rows/wave -> 10000 waves total
    const int wv = threadIdx.x >> 6;
    const int lane = threadIdx.x & 63;
    const int row0 = b * 8 + wv * 2;
    float a0 = 0.f, a1 = 0.f;
    if (!flags[0]) {
      const bf16_t* xb = (const bf16_t*)x + (long)row0 * FIN;
      const bf16_t* wp = (const bf16_t*)W1;
#pragma unroll 4
      for (int k8 = 0; k8 < FIN / 8; ++k8) {
        us8 r0 = *(const us8*)(xb + k8 * 8);
        us8 r1 = *(const us8*)(xb + FIN + k8 * 8);
#pragma unroll
        for (int q = 0; q < 8; ++q) {
          float w = b2f(wp[(k8 * 8 + q) * HID + lane]);
          a0 += b2f(r0[q]) * w;
          a1 += b2f(r1[q]) * w;
        }
      }
    } else {
      const float* x0 = (const float*)x + (long)row0 * FIN;
      const float* wp = (const float*)W1;
#pragma unroll 8
      for (int k = 0; k < FIN; ++k) {
        float w = wp[k * HID + lane];
        a0 += x0[k] * w;
        a1 += x0[FIN + k] * w;
      }
    }
    xw1[(long)(row0 + 0) * HID + lane] = a0;
    xw1[(long)(row0 + 1) * HID + lane] = a1;
  } else {
    // scatter: pos becomes in-degree, slot holds sources
    int i = (b - GB1) * 256 + threadIdx.x;
    if (i < EE) {
      int i64 = flags[1];
      int s = ldi(ei, i, i64);
      int d = ldi(ei, (long)EE + i, i64);
      int p = atomicAdd(&pos[d], 1);
      if (p < CAP) slot[d * CAP + p] = s;
    }
  }
}

// ---------- gather A: h1 = relu(Agg(xw1)+b1); xw2 = h1 @ W2 (in-wave GEMV) --
__global__ __launch_bounds__(256) void gatherA_kernel(const float* __restrict__ xw,
                                                      const int* __restrict__ cnt,
                                                      const int* __restrict__ slot,
                                                      float* __restrict__ xw2,
                                                      const void* __restrict__ b1v,
                                                      const void* __restrict__ W2,
                                                      const int* __restrict__ flags) {
  int n = blockIdx.x * 4 + (threadIdx.x >> 6);
  if (n >= NN) return;
  int fF = flags[0];
  int c = threadIdx.x & 63;
  float dn = rsqrtf((float)cnt[n] + 1.0f);
  float acc = xw[(long)n * HID + c] * dn;      // self term
  int m = cnt[n]; if (m > CAP) m = CAP;
  const int* sl = slot + (long)n * CAP;
  float accB = 0.f;
  for (int e0 = 0; e0 < m; e0 += 8) {
    int4 sa = *(const int4*)(sl + e0);
    int4 sb = *(const int4*)(sl + e0 + 4);
    if (e0 + 0 < m) acc  += xw[(long)sa.x * HID + c] * rsqrtf((float)cnt[sa.x] + 1.0f);
    if (e0 + 1 < m) accB += xw[(long)sa.y * HID + c] * rsqrtf((float)cnt[sa.y] + 1.0f);
    if (e0 + 2 < m) acc  += xw[(long)sa.z * HID + c] * rsqrtf((float)cnt[sa.z] + 1.0f);
    if (e0 + 3 < m) accB += xw[(long)sa.w * HID + c] * rsqrtf((float)cnt[sa.w] + 1.0f);
    if (e0 + 4 < m) acc  += xw[(long)sb.x * HID + c] * rsqrtf((float)cnt[sb.x] + 1.0f);
    if (e0 + 5 < m) accB += xw[(long)sb.y * HID + c] * rsqrtf((float)cnt[sb.y] + 1.0f);
    if (e0 + 6 < m) acc  += xw[(long)sb.z * HID + c] * rsqrtf((float)cnt[sb.z] + 1.0f);
    if (e0 + 7 < m) accB += xw[(long)sb.w * HID + c] * rsqrtf((float)cnt[sb.w] + 1.0f);
  }
  float h1 = (acc + accB) * dn + ldf(b1v, c, fF);
  h1 = h1 > 0.f ? h1 : 0.f;                     // relu'd hidden, channel c

  // xw2[n][c] = sum_k h1[k] * W2[k][c]  via 64 wave broadcasts
  float o = 0.f;
#pragma unroll 8
  for (int k = 0; k < HID; ++k)
    o += __shfl(h1, k) * ldf(W2, k * HID + c, fF);
  xw2[(long)n * HID + c] = o;
}

// ---------- gather B: h2 = Agg(xw2); n2 = ||h2+b2||^2 ----------
__global__ __launch_bounds__(256) void gatherB_kernel(const float* __restrict__ xw,
                                                      const int* __restrict__ cnt,
                                                      const int* __restrict__ slot,
                                                      float* __restrict__ h,
                                                      float* __restrict__ n2,
                                                      const void* __restrict__ b2v,
                                                      const int* __restrict__ flags) {
  int n = blockIdx.x * 4 + (threadIdx.x >> 6);
  if (n >= NN) return;
  int c = threadIdx.x & 63;
  float dn = rsqrtf((float)cnt[n] + 1.0f);
  float acc = xw[(long)n * HID + c] * dn;
  int m = cnt[n]; if (m > CAP) m = CAP;
  const int* sl = slot + (long)n * CAP;
  float accB = 0.f;
  for (int e0 = 0; e0 < m; e0 += 8) {
    int4 sa = *(const int4*)(sl + e0);
    int4 sb = *(const int4*)(sl + e0 + 4);
    if (e0 + 0 < m) acc  += xw[(long)sa.x * HID + c] * rsqrtf((float)cnt[sa.x] + 1.0f);
    if (e0 + 1 < m) accB += xw[(long)sa.y * HID + c] * rsqrtf((float)cnt[sa.y] + 1.0f);
    if (e0 + 2 < m) acc  += xw[(long)sa.z * HID + c] * rsqrtf((float)cnt[sa.z] + 1.0f);
    if (e0 + 3 < m) accB += xw[(long)sa.w * HID + c] * rsqrtf((float)cnt[sa.w] + 1.0f);
    if (e0 + 4 < m) acc  += xw[(long)sb.x * HID + c] * rsqrtf((float)cnt[sb.x] + 1.0f);
    if (e0 + 5 < m) accB += xw[(long)sb.y * HID + c] * rsqrtf((float)cnt[sb.y] + 1.0f);
    if (e0 + 6 < m) acc  += xw[(long)sb.z * HID + c] * rsqrtf((float)cnt[sb.z] + 1.0f);
    if (e0 + 7 < m) accB += xw[(long)sb.w * HID + c] * rsqrtf((float)cnt[sb.w] + 1.0f);
  }
  acc = (acc + accB) * dn;
  h[(long)n * HID + c] = acc;
  float v = acc + ldf(b2v, c, flags[0]);
  float s = v * v;
  s += __shfl_xor(s, 1); s += __shfl_xor(s, 2); s += __shfl_xor(s, 4);
  s += __shfl_xor(s, 8); s += __shfl_xor(s, 16); s += __shfl_xor(s, 32);
  if (c == 0) n2[n] = s;
}

// ---------- FGW: 4 nodes/block, 8-lane octet per (node, template) ----------
#define NODES_PB 4
#define TPN 80            // threads per node (10 templates x 8 lanes)
#define XLP 65            // padded xl row stride

__global__ __launch_bounds__(320, 2) void fgw_kernel(
    const float* __restrict__ h2,        // [NN,64] fp32 ws (pre-b2)
    const void* __restrict__ b2v,
    const void* __restrict__ nbr_idx,
    const void* __restrict__ nbr_mask,
    const void* __restrict__ C_local,
    const void* __restrict__ tmpl,       // [10,8,8]
    const void* __restrict__ tfeat,      // [10,8,64]
    const void* __restrict__ Wlin,       // [74,6]
    const void* __restrict__ blin,       // [6]
    void* __restrict__ out,              // [NN,6]
    const int* __restrict__ flags,
    const float* __restrict__ tn2min,    // [11]: per-t mins + global min
    const float* __restrict__ n2)        // [NN] node norm^2
{
  const int tid = threadIdx.x;
  const int fF = flags[0];
  const int fI = flags[1];
  const int nb = tid / TPN;
  const int local = tid - nb * TPN;      // [0,80)
  const int t = local >> 3;
  const int j = local & 7;
  const int n = blockIdx.x * NODES_PB + nb;
  const int lane = tid & 63;
  const int ob = lane & 56;

  __shared__ float xlS[NODES_PB][LSZ][XLP];
  __shared__ float C1S[NODES_PB][81];
  __shared__ float hwS[NODES_PB][LSZ];
  __shared__ float f1S[NODES_PB][LSZ];
  __shared__ float xnS[NODES_PB][LSZ];
  __shared__ float distS[NODES_PB][NTPL];
  __shared__ float xmaxS[NODES_PB];
  __shared__ int   needS[NODES_PB];
  __shared__ int   sidxS[NODES_PB][LSZ];
  __shared__ float WlinS[(HID + NTPL) * NCLS + NCLS];   // Wlin + blin

  for (int i = tid; i < (HID + NTPL) * NCLS; i += 320)
    WlinS[i] = ldf(Wlin, i, fF);
  if (tid < NCLS) WlinS[(HID + NTPL) * NCLS + tid] = ldf(blin, tid, fF);

  if (local < LSZ) {
    int idx = (local == 0) ? n : ldi(nbr_idx, (long)n * KNEI + local - 1, fI);
    sidxS[nb][local] = idx;
    xnS[nb][local] = n2[idx];
  }
  if (local < HID)
    xlS[nb][0][local] = h2[(long)n * HID + local] + ldf(b2v, local, fF);
  __syncthreads();   // B1

  if (local == 0) {
    float xm = xnS[nb][0];
#pragma unroll
    for (int l = 1; l < LSZ; ++l) xm = fmaxf(xm, xnS[nb][l]);
    xmaxS[nb] = xm;
    needS[nb] = ((sqrtf(tn2min[NTPL]) - sqrtf(xm)) >= 5.0990195f) ? 0 : 1;
  }
  __syncthreads();   // B2

  const int need = needS[nb];
  if (need) {
    for (int i = local; i < 8 * HID; i += TPN) {
      int l = 1 + (i >> 6), k = i & 63;
      xlS[nb][l][k] = h2[(long)sidxS[nb][l] * HID + k] + ldf(b2v, k, fF);
    }
    for (int i = local; i < 81; i += TPN)
      C1S[nb][i] = ldf(C_local, (long)n * 81 + i, fF);
  }
  __syncthreads();   // B3

  if (need && local < LSZ) {
    int l = local;
    float msum = 0.f, f1 = 0.f;
#pragma unroll
    for (int jj = 0; jj < LSZ; ++jj) {
      float mj = ldf(nbr_mask, (long)n * LSZ + jj, fF);
      msum += mj;
      float c = C1S[nb][l * LSZ + jj];
      f1 += c * c * mj;
    }
    float inv = frcp(msum);
    hwS[nb][l] = ldf(nbr_mask, (long)n * LSZ + l, fF) * inv;
    f1S[nb][l] = f1 * inv;
  }
  __syncthreads();   // B4

  bool slow = need && ((sqrtf(tn2min[t]) - sqrtf(xmaxS[nb])) < 5.0990195f);
  if (slow) {
    float C2c[NTN];
    float f2h2;
    {
      float s = 0.f;
#pragma unroll
      for (int m = 0; m < NTN; ++m) {
        C2c[m] = ldf(tmpl, t * 64 + m * 8 + j, fF);
        float r = ldf(tmpl, t * 64 + j * 8 + m, fF);
        s += r * r;
      }
      f2h2 = s * 0.125f;
    }
    float hwr[LSZ], f1r[LSZ];
#pragma unroll
    for (int l = 0; l < LSZ; ++l) { hwr[l] = hwS[nb][l]; f1r[l] = f1S[nb][l]; }

    float Mc[LSZ];
    {
      float accI[LSZ];
#pragma unroll
      for (int l = 0; l < LSZ; ++l) accI[l] = 0.f;
      float tn2 = 0.f;
      const long tb = (long)local * HID;
      for (int kb = 0; kb < 8; ++kb) {
        float r[8];
#pragma unroll
        for (int q = 0; q < 8; ++q) r[q] = ldf(tfeat, tb + kb * 8 + q, fF);
#pragma unroll
        for (int q = 0; q < 8; ++q) tn2 += r[q] * r[q];
#pragma unroll
        for (int l = 0; l < LSZ; ++l) {
          float s = 0.f;
#pragma unroll
          for (int q = 0; q < 8; ++q) s += xlS[nb][l][kb * 8 + q] * r[q];
          accI[l] += s;
        }
      }
#pragma unroll
      for (int l = 0; l < LSZ; ++l)
        Mc[l] = xnS[nb][l] + tn2 - 2.f * accI[l];
    }

    float Tc[LSZ], Kc[LSZ], u[LSZ];
#pragma unroll
    for (int l = 0; l < LSZ; ++l) Tc[l] = hwr[l] * 0.125f;

    float v = 1.0f;
    for (int outer = 0; outer < 3; ++outer) {
      float Ac[LSZ];
#pragma unroll
      for (int l = 0; l < LSZ; ++l) {
        float s = 0.f;
#pragma unroll
        for (int l2 = 0; l2 < LSZ; ++l2) s += C1S[nb][l * LSZ + l2] * Tc[l2];
        Ac[l] = s;
      }
#pragma unroll
      for (int l = 0; l < LSZ; ++l) {
        float s = 0.f;
#pragma unroll
        for (int m = 0; m < NTN; ++m) s += __shfl(Ac[l], ob + m) * C2c[m];
        float tens = f1r[l] + f2h2 - 2.f * s;
        Kc[l] = __expf(-5.0f * (Mc[l] + tens));
      }
      v = 1.0f;
      for (int it = 0; it < 5; ++it) {
#pragma unroll
        for (int l = 0; l < LSZ; ++l) {
          float p = Kc[l] * v;
          p += __shfl_xor(p, 1); p += __shfl_xor(p, 2); p += __shfl_xor(p, 4);
          u[l] = hwr[l] * frcp(p + 1e-16f);
        }
        float s = 0.f;
#pragma unroll
        for (int l = 0; l < LSZ; ++l) s += Kc[l] * u[l];
        v = 0.125f * frcp(s + 1e-16f);
      }
#pragma unroll
      for (int l = 0; l < LSZ; ++l) Tc[l] = u[l] * Kc[l] * v;
    }
    {
      float Ac[LSZ];
#pragma unroll
      for (int l = 0; l < LSZ; ++l) {
        float s = 0.f;
#pragma unroll
        for (int l2 = 0; l2 < LSZ; ++l2) s += C1S[nb][l * LSZ + l2] * Tc[l2];
        Ac[l] = s;
      }
      float cl = 0.f;
#pragma unroll
      for (int l = 0; l < LSZ; ++l) {
        float s = 0.f;
#pragma unroll
        for (int m = 0; m < NTN; ++m) s += __shfl(Ac[l], ob + m) * C2c[m];
        float tens = f1r[l] + f2h2 - 2.f * s;
        cl += Tc[l] * 0.5f * (Mc[l] + tens);
      }
      cl += __shfl_xor(cl, 1); cl += __shfl_xor(cl, 2); cl += __shfl_xor(cl, 4);
      if (j == 0) distS[nb][t] = cl;
    }
  } else if (j == 0) {
    distS[nb][t] = 0.f;
  }
  __syncthreads();   // B5

  if (local < NCLS) {
    int c = local;
    float acc = WlinS[(HID + NTPL) * NCLS + c];
#pragma unroll
    for (int k = 0; k < HID; ++k)
      acc += xlS[nb][0][k] * WlinS[k * NCLS + c];
#pragma unroll
    for (int tt = 0; tt < NTPL; ++tt)
      acc += distS[nb][tt] * WlinS[(HID + tt) * NCLS + c];
    float r = acc > 0.f ? acc : 0.f;
    if (fF) ((float*)out)[(long)n * NCLS + c] = r;
    else    ((bf16_t*)out)[(long)n * NCLS + c] = f2b(r);
  }
}

extern "C" void kernel_launch(void* const* d_in, const int* in_sizes, int n_in,
                              void* d_out, int out_size, void* d_ws, size_t ws_size,
                              hipStream_t stream) {
  (void)in_sizes; (void)n_in; (void)out_size; (void)ws_size;
  const void* x     = d_in[0];
  const void* ei    = d_in[1];
  const void* nbr   = d_in[2];
  const void* nmask = d_in[3];
  const void* Cl    = d_in[4];
  const void* W1    = d_in[5];
  const void* b1    = d_in[6];
  const void* W2    = d_in[7];
  const void* b2    = d_in[8];
  const void* tmpl  = d_in[9];
  const void* tfeat = d_in[10];
  const void* Wlin  = d_in[11];
  const void* blin  = d_in[12];

  // ws layout (4B words): flags[4] | tn2min[12] | n2 NN | pos NN |
  //                       slot CAP*NN | bufA 64NN | bufB 64NN
  int*   flags  = (int*)d_ws;
  float* tn2min = (float*)d_ws + 4;
  float* n2     = (float*)d_ws + 16;
  int*   pos    = (int*)(n2 + NN);
  int*   slot   = pos + NN;
  float* bufA   = (float*)(slot + (long)CAP * NN);
  float* bufB   = bufA + (long)NN * HID;

  probe_kernel<<<1, 128, 0, stream>>>(x, ei, tfeat, flags, tn2min);
  hipMemsetAsync(pos, 0, NN * sizeof(int), stream);

  // fused gemm1 + scatter (independent work, block-range split)
  work1_kernel<<<GB1 + SB1, 256, 0, stream>>>(x, W1, bufA, ei, pos, slot, flags);

  // gather A: aggregate xw1 -> relu(h1) -> in-wave GEMV with W2 -> xw2 (bufB)
  gatherA_kernel<<<NN / 4, 256, 0, stream>>>(bufA, pos, slot, bufB, b1, W2, flags);
  // gather B: aggregate xw2 -> h2 (bufA) + n2
  gatherB_kernel<<<NN / 4, 256, 0, stream>>>(bufB, pos, slot, bufA, n2, b2, flags);

  fgw_kernel<<<NN / NODES_PB, 320, 0, stream>>>(bufA, b2, nbr, nmask, Cl, tmpl,
                                                tfeat, Wlin, blin, d_out, flags,
                                                tn2min, n2);
}